// Round 15
// baseline (129.833 us; speedup 1.0000x reference)
//
#include <hip/hip_runtime.h>

#define N 4096
#define D 1024
#define BMR 64      // tile rows per block (smaller tile -> more resident blocks)
#define BN 128      // tile cols per block
#define BKB 128     // K-bytes (= fp8 elements) per stage = one MX K-window
#define NSLOT 64    // N / BMR partial-slots per column

typedef float floatx4 __attribute__((ext_vector_type(4)));
typedef int intx8 __attribute__((ext_vector_type(8)));
union frag8 { intx8 v; int4 q[2]; };

// ---------------------------------------------------------------------------
// Kernel 1: fp32 -> fp8 e4m3 (scaled x32; pow2 -> exact to undo) + row norms.
// One wave per row. Thread (0,0) zero-inits d_out for the atomic finalize.
// ---------------------------------------------------------------------------
__global__ __launch_bounds__(256) void prep_kernel(const float* __restrict__ x,
                                                   unsigned char* __restrict__ xq,
                                                   float* __restrict__ sq,
                                                   float* __restrict__ out) {
    if (blockIdx.x == 0 && threadIdx.x == 0) {
        out[0] = 0.f; out[1] = 0.f; out[2] = 0.f; out[3] = 0.f;
    }
    int row = blockIdx.x * 4 + (threadIdx.x >> 6);
    int lane = threadIdx.x & 63;
    const float4* xr = (const float4*)(x + (size_t)row * D);
    unsigned int* qr = (unsigned int*)(xq + (size_t)row * D);
    float s = 0.f;
    #pragma unroll
    for (int j = 0; j < 4; ++j) {
        float4 v = xr[j * 64 + lane];
        s += v.x * v.x + v.y * v.y + v.z * v.z + v.w * v.w;
        // OCP e4m3 pack, values scaled by 32 (sigma ~1.0, no subnormals)
        unsigned int w = __builtin_amdgcn_cvt_pk_fp8_f32(v.x * 32.f, v.y * 32.f, 0, false);
        w = __builtin_amdgcn_cvt_pk_fp8_f32(v.z * 32.f, v.w * 32.f, w, true);
        qr[j * 64 + lane] = w;
    }
    #pragma unroll
    for (int sh = 1; sh < 64; sh <<= 1) s += __shfl_xor(s, sh);
    if (lane == 0) sq[row] = s;
}

// ---------------------------------------------------------------------------
// Kernel 2: fused X.X^T GEMM via MX-scaled fp8 MFMA (16x16x128, scales=1.0)
// + dist + masked exp COLUMN-reductions.
// Round-15 change: 64x128 TILE, 2048 blocks, __launch_bounds__(256,4).
// Rationale: R10's 128x128 tile runs at 2 blocks/CU; the barrier vmcnt(0)
// drain stalls are an occupancy-coverage problem (m114: implicit block-level
// overlap hides drains). Halving the tile halves acc regs (32) and LDS
// (24 KB) -> 4 resident blocks/CU, doubling drain coverage. MFMA count
// unchanged. Wave w computes 64 x 32 (cols w*32..w*32+31): acc[4][2].
// LDS: A tile 8 KB (4 groups) then B tile 16 KB (8 groups); 2KB group =
// 16 rows x 8 chunks(16B); chunk c of row r at slot c ^ (r&7):
//  (a) staging quarter-waves cover full 128B row segments (coalesced)
//  (b) fragment ds_read_b128: XOR bijection over chunks -> conflict-free
// dot_real = acc * 2^-10 (undo the x32 input scaling exactly).
// ---------------------------------------------------------------------------
__global__ __launch_bounds__(256, 4) void gemm_fused(const unsigned char* __restrict__ xq,
                                                     const float* __restrict__ sq,
                                                     float* __restrict__ colPart) {
    __shared__ __align__(16) unsigned char smem[(BMR + BN) * BKB];   // 24 KB

    const int bi = blockIdx.y, bj = blockIdx.x;     // 64 x 32 grid
    const int i0 = bi * BMR, j0 = bj * BN;
    const int tid = threadIdx.x;
    const int lane = tid & 63, wn = tid >> 6;       // 4 waves over 128 cols
    const int quad = lane >> 4, c16 = lane & 15;

    // staging source byte offsets: 1536 chunks of 16B (A 512, B 1024)
    int goff[6];
    #pragma unroll
    for (int it = 0; it < 6; ++it) {
        int chunk = it * 256 + tid;
        int isB = chunk >= 512;                    // wave-uniform (64 | 512)
        int c = isB ? chunk - 512 : chunk;
        int g = c >> 7, p = c & 127;               // groups of (16 rows x 8 chunks)
        int r = p >> 3, ch = p & 7;
        int grow = (isB ? j0 : i0) + g * 16 + r;
        goff[it] = grow * D + ((ch ^ (r & 7)) << 4);   // byte offset; += kt
    }
    // fragment LDS offsets: lane reads chunks 2*quad, 2*quad+1 of row c16
    const int rowb = c16 * 128;
    const int fo0 = ((2 * quad + 0) ^ (c16 & 7)) * 16;
    const int fo1 = ((2 * quad + 1) ^ (c16 & 7)) * 16;

    floatx4 acc[4][2];
    #pragma unroll
    for (int a = 0; a < 4; ++a)
        #pragma unroll
        for (int b = 0; b < 2; ++b) acc[a][b] = (floatx4){0.f, 0.f, 0.f, 0.f};

    for (int kt = 0; kt < D; kt += BKB) {    // 8 stages, single-buffered
        #pragma unroll
        for (int it = 0; it < 6; ++it) {
            const unsigned char* gp = xq + goff[it] + kt;
            unsigned char* lp = smem + (it * 256 + tid) * 16;
            __builtin_amdgcn_global_load_lds(
                (const __attribute__((address_space(1))) void*)gp,
                (__attribute__((address_space(3))) void*)lp, 16, 0, 0);
        }
        __syncthreads();   // drains vmcnt -> LDS tiles ready

        frag8 bf[2];
        #pragma unroll
        for (int tn = 0; tn < 2; ++tn) {
            // B group = wn*2 + tn (8 groups of 16 rows), base 8192
            const unsigned char* bp = smem + 8192 + (wn * 2 + tn) * 2048 + rowb;
            bf[tn].q[0] = *(const int4*)(bp + fo0);
            bf[tn].q[1] = *(const int4*)(bp + fo1);
        }
        #pragma unroll
        for (int tm = 0; tm < 4; ++tm) {
            const unsigned char* ap = smem + tm * 2048 + rowb;   // A group = tm
            frag8 af;
            af.q[0] = *(const int4*)(ap + fo0);
            af.q[1] = *(const int4*)(ap + fo1);
            #pragma unroll
            for (int tn = 0; tn < 2; ++tn)
                acc[tm][tn] = __builtin_amdgcn_mfma_scale_f32_16x16x128_f8f6f4(
                    af.v, bf[tn].v, acc[tm][tn],
                    0, 0,                    // cbsz/blgp: fp8 e4m3 A and B
                    0, 0x7f7f7f7f,           // opsel_a, scale_a = 1.0 (E8M0 127)
                    0, 0x7f7f7f7f);          // opsel_b, scale_b = 1.0
        }
        __syncthreads();   // protect LDS before next stage overwrites
    }

    // ---- epilogue: column partial sums ----
    // C/D layout shape-determined: col = c16, row = quad*4 + r  [m89/m127/m128]
    float sqi[4][4];
    #pragma unroll
    for (int tm = 0; tm < 4; ++tm)
        #pragma unroll
        for (int r = 0; r < 4; ++r)
            sqi[tm][r] = sq[i0 + tm * 16 + quad * 4 + r];
    float sqj[2];
    #pragma unroll
    for (int tn = 0; tn < 2; ++tn)
        sqj[tn] = sq[j0 + wn * 32 + tn * 16 + c16];

    float cpa[2], cna[2], cpb[2], cnb[2], cpd[2], cnd[2];
    // same-class pairs only where the 64-row block meets its own 128-col block
    const bool diag = ((bi >> 1) == bj);
    const float DS = -0.001953125f; // -2 * 2^-10: undo x32 input scaling

    #pragma unroll
    for (int tn = 0; tn < 2; ++tn) {
        float pa = 0.f, na = 0.f, pb = 0.f, nb = 0.f, pd = 0.f, nd = 0.f;
        if (!diag) {
            // pure negatives: branch-free
            #pragma unroll
            for (int tm = 0; tm < 4; ++tm)
                #pragma unroll
                for (int r = 0; r < 4; ++r) {
                    float dot = acc[tm][tn][r];
                    float dsq = fmaf(dot, DS, sqi[tm][r] + sqj[tn]);
                    float dist = sqrtf(fmaxf(dsq, 1e-12f));
                    float t = __expf(20.0f * (1.1f - dist));   // exp(BETA(1.1-d))
                    na = fmaf(t, t, na);                        // e^4 * exp(40(1-d))
                    nb += t;
                    nd += dist;
                }
        } else {
            const int gj = j0 + wn * 32 + tn * 16 + c16;
            const int gjc = gj >> 3;
            #pragma unroll
            for (int tm = 0; tm < 4; ++tm)
                #pragma unroll
                for (int r = 0; r < 4; ++r) {
                    const int gi = i0 + tm * 16 + quad * 4 + r;
                    float dot = acc[tm][tn][r];
                    float dsq = fmaf(dot, DS, sqi[tm][r] + sqj[tn]);
                    float dist = sqrtf(fmaxf(dsq, 1e-12f));
                    float t = __expf(20.0f * (1.1f - dist));
                    bool same = (gi >> 3) == gjc;
                    if (same) {
                        if (gi != gj) {
                            pa = fmaf(t, t, pa);
                            pb += __expf(20.0f * (dist - 0.8f));
                            pd += dist;
                        }
                    } else {
                        na = fmaf(t, t, na);
                        nb += t;
                        nd += dist;
                    }
                }
        }
        cpa[tn] = pa; cna[tn] = na; cpb[tn] = pb;
        cnb[tn] = nb; cpd[tn] = pd; cnd[tn] = nd;
    }

    // reduce the 4 quads (each column's 64 rows): lanes ^16, ^32 only
    #pragma unroll
    for (int tn = 0; tn < 2; ++tn) {
        #pragma unroll
        for (int s = 16; s < 64; s <<= 1) {
            cna[tn] += __shfl_xor(cna[tn], s);
            cnb[tn] += __shfl_xor(cnb[tn], s);
            cnd[tn] += __shfl_xor(cnd[tn], s);
        }
        if (diag) {
            #pragma unroll
            for (int s = 16; s < 64; s <<= 1) {
                cpa[tn] += __shfl_xor(cpa[tn], s);
                cpb[tn] += __shfl_xor(cpb[tn], s);
                cpd[tn] += __shfl_xor(cpd[tn], s);
            }
        }
    }

    // single wave-row: write column sums straight to LDS (no half-combine)
    float* colBuf = (float*)smem;   // [128][6] floats = 3 KB
    #pragma unroll
    for (int tn = 0; tn < 2; ++tn) {
        // all 4 quads hold identical reduced values; same-addr same-value writes
        int cb = (wn * 32 + tn * 16 + c16) * 6;
        colBuf[cb + 0] = cpa[tn]; colBuf[cb + 1] = cna[tn];
        colBuf[cb + 2] = cpb[tn]; colBuf[cb + 3] = cnb[tn];
        colBuf[cb + 4] = cpd[tn]; colBuf[cb + 5] = cnd[tn];
    }
    __syncthreads();

    // atomic-free partial store: contiguous 3 KB per block
    float* dst = colPart + (size_t)bi * N * 6 + (size_t)j0 * 6;
    #pragma unroll
    for (int it = 0; it < 3; ++it) {
        int idx = it * 256 + tid;               // 0..767
        dst[idx] = colBuf[idx];
    }
}

// ---------------------------------------------------------------------------
// Kernel 3: reduce the 64 per-block partial slots -> per-row loss pieces,
// then block-reduce and atomically accumulate the 3 global means into out.
// (out zero-initialized by prep_kernel; stream serialization guarantees order)
// ---------------------------------------------------------------------------
__global__ __launch_bounds__(256) void reduce_finalize(const float* __restrict__ colPart,
                                                       float* __restrict__ out) {
    int j = blockIdx.x * 256 + threadIdx.x;     // 4096 threads total
    float pa = 0.f, na = 0.f, pb = 0.f, nb = 0.f, pd = 0.f, nd = 0.f;
    for (int s = 0; s < NSLOT; ++s) {
        const float* p = colPart + (size_t)s * N * 6 + (size_t)j * 6;
        pa += p[0]; na += p[1]; pb += p[2];
        nb += p[3]; pd += p[4]; nd += p[5];
    }
    // pa/na both carry the same e^4 factor vs exp(40(1-d)) -> cancels in a_lr
    float a_lr = 1.0f - pa / (pa + na);
    float L = a_lr * (logf(pb) + logf(nb));

    #pragma unroll
    for (int s = 1; s < 64; s <<= 1) {
        L  += __shfl_xor(L, s);
        pd += __shfl_xor(pd, s);
        nd += __shfl_xor(nd, s);
    }
    __shared__ float r0[4], r1[4], r2[4];
    int lane = threadIdx.x & 63, w = threadIdx.x >> 6;
    if (lane == 0) { r0[w] = L; r1[w] = pd; r2[w] = nd; }
    __syncthreads();
    if (threadIdx.x == 0) {
        float Ls = r0[0] + r0[1] + r0[2] + r0[3];
        float Ps = r1[0] + r1[1] + r1[2] + r1[3];
        float Gs = r2[0] + r2[1] + r2[2] + r2[3];
        atomicAdd(out + 0, Ls / (float)N);
        atomicAdd(out + 2, Ps / ((float)N * 7.0f));              // 7 pos pairs/row
        atomicAdd(out + 3, Gs / ((float)N * (float)(N - 8)));    // 4088 neg/row
        // out[1] (accuracy) stays 0 from prep's init
    }
}

// ---------------------------------------------------------------------------
extern "C" void kernel_launch(void* const* d_in, const int* in_sizes, int n_in,
                              void* d_out, int out_size, void* d_ws, size_t ws_size,
                              hipStream_t stream) {
    const float* x = (const float*)d_in[0];
    float* out = (float*)d_out;
    char* ws = (char*)d_ws;

    unsigned char* xq = (unsigned char*)ws;                          // 4 MB fp8 matrix
    float* sq         = (float*)(ws + (size_t)N * D);                // 16 KB row norms
    float* colPart    = (float*)(ws + (size_t)N * D + N * 4);        // 6.3 MB partials

    prep_kernel<<<N / 4, 256, 0, stream>>>(x, xq, sq, out);

    dim3 grid(N / BN, N / BMR);
    gemm_fused<<<grid, 256, 0, stream>>>(xq, sq, colPart);

    reduce_finalize<<<N / 256, 256, 0, stream>>>(colPart, out);
}

// Round 16
// 101.034 us; speedup vs baseline: 1.2850x; 1.2850x over previous
//
#include <hip/hip_runtime.h>

#define N 4096
#define D 1024
#define BM 128
#define BN 128
#define BKB 128     // K-bytes (= fp8 elements) per stage = one MX K-window
#define NSLOT 32    // N / BM partial-slots per column

typedef float floatx4 __attribute__((ext_vector_type(4)));
typedef int intx8 __attribute__((ext_vector_type(8)));
union frag8 { intx8 v; int4 q[2]; };

// ---------------------------------------------------------------------------
// Kernel 1: fp32 -> fp8 e4m3 (scaled x32; pow2 -> exact to undo) + row norms.
// One wave per row. Thread (0,0) zero-inits d_out for the atomic finalize.
// ---------------------------------------------------------------------------
__global__ __launch_bounds__(256) void prep_kernel(const float* __restrict__ x,
                                                   unsigned char* __restrict__ xq,
                                                   float* __restrict__ sq,
                                                   float* __restrict__ out) {
    if (blockIdx.x == 0 && threadIdx.x == 0) {
        out[0] = 0.f; out[1] = 0.f; out[2] = 0.f; out[3] = 0.f;
    }
    int row = blockIdx.x * 4 + (threadIdx.x >> 6);
    int lane = threadIdx.x & 63;
    const float4* xr = (const float4*)(x + (size_t)row * D);
    unsigned int* qr = (unsigned int*)(xq + (size_t)row * D);
    float s = 0.f;
    #pragma unroll
    for (int j = 0; j < 4; ++j) {
        float4 v = xr[j * 64 + lane];
        s += v.x * v.x + v.y * v.y + v.z * v.z + v.w * v.w;
        // OCP e4m3 pack, values scaled by 32 (sigma ~1.0, no subnormals)
        unsigned int w = __builtin_amdgcn_cvt_pk_fp8_f32(v.x * 32.f, v.y * 32.f, 0, false);
        w = __builtin_amdgcn_cvt_pk_fp8_f32(v.z * 32.f, v.w * 32.f, w, true);
        qr[j * 64 + lane] = w;
    }
    #pragma unroll
    for (int sh = 1; sh < 64; sh <<= 1) s += __shfl_xor(s, sh);
    if (lane == 0) sq[row] = s;
}

// ---------------------------------------------------------------------------
// Kernel 2 (round-10 best, final): fused X.X^T GEMM via MX-scaled fp8
// MFMA (16x16x128 f8f6f4, scales = 1.0 so opsel/scale mapping is irrelevant)
// + dist + masked exp COLUMN-reductions. Single-buffered LDS staging,
// 128x128 tile (the measured reuse sweet spot: 64x128 quadrupled HBM fetch,
// R15). Measured best among {bf16 BK32/64, fp8 non-scaled, MX+dbuf,
// MX+fusion, MX+direct-load, 64x128 tile} across rounds 2-15.
// LDS: 2KB group = 16 rows x 8 chunks(16B); chunk c of row r at slot
// c ^ (r&7):
//  (a) staging quarter-waves cover full 128B row segments (coalesced)
//  (b) fragment ds_read_b128: XOR bijection over chunks -> conflict-free
// dot_real = acc * 2^-10 (undo the x32 input scaling exactly).
// ---------------------------------------------------------------------------
__global__ __launch_bounds__(256, 2) void gemm_fused(const unsigned char* __restrict__ xq,
                                                     const float* __restrict__ sq,
                                                     float* __restrict__ colPart) {
    __shared__ __align__(16) unsigned char smem[2 * BM * BKB];   // 32 KB

    const int bi = blockIdx.y, bj = blockIdx.x;
    const int i0 = bi * BM, j0 = bj * BN;
    const int tid = threadIdx.x;
    const int lane = tid & 63, wave = tid >> 6;
    const int wm = wave >> 1, wn = wave & 1;        // 2x2 waves over 128x128
    const int quad = lane >> 4, c16 = lane & 15;

    // staging source byte offsets (slot = lane position, content per swizzle)
    int goff[8];
    #pragma unroll
    for (int it = 0; it < 8; ++it) {
        int chunk = it * 256 + tid;          // 2048 chunks of 16B per stage
        int half = chunk >> 10;              // 0 = A, 1 = B (wave-uniform)
        int c = chunk & 1023;
        int g = c >> 7, s = c & 127;         // 8 groups of (16 rows x 8 chunks)
        int r = s >> 3, ch = s & 7;
        int grow = (half ? j0 : i0) + g * 16 + r;
        goff[it] = grow * D + ((ch ^ (r & 7)) << 4);   // byte offset; += kt
    }
    // fragment LDS offsets: lane reads chunks 2*quad, 2*quad+1 of row c16
    const int rowb = c16 * 128;
    const int fo0 = ((2 * quad + 0) ^ (c16 & 7)) * 16;
    const int fo1 = ((2 * quad + 1) ^ (c16 & 7)) * 16;

    floatx4 acc[4][4];
    #pragma unroll
    for (int a = 0; a < 4; ++a)
        #pragma unroll
        for (int b = 0; b < 4; ++b) acc[a][b] = (floatx4){0.f, 0.f, 0.f, 0.f};

    for (int kt = 0; kt < D; kt += BKB) {    // 8 stages, single-buffered
        #pragma unroll
        for (int it = 0; it < 8; ++it) {
            const unsigned char* gp = xq + goff[it] + kt;
            unsigned char* lp = smem + (it * 256 + tid) * 16;
            __builtin_amdgcn_global_load_lds(
                (const __attribute__((address_space(1))) void*)gp,
                (__attribute__((address_space(3))) void*)lp, 16, 0, 0);
        }
        __syncthreads();   // drains vmcnt -> LDS tiles ready

        frag8 bf[4];
        #pragma unroll
        for (int tn = 0; tn < 4; ++tn) {
            const unsigned char* bp = smem + 16384 + (wn * 4 + tn) * 2048 + rowb;
            bf[tn].q[0] = *(const int4*)(bp + fo0);
            bf[tn].q[1] = *(const int4*)(bp + fo1);
        }
        #pragma unroll
        for (int tm = 0; tm < 4; ++tm) {
            const unsigned char* ap = smem + (wm * 4 + tm) * 2048 + rowb;
            frag8 af;
            af.q[0] = *(const int4*)(ap + fo0);
            af.q[1] = *(const int4*)(ap + fo1);
            #pragma unroll
            for (int tn = 0; tn < 4; ++tn)
                acc[tm][tn] = __builtin_amdgcn_mfma_scale_f32_16x16x128_f8f6f4(
                    af.v, bf[tn].v, acc[tm][tn],
                    0, 0,                    // cbsz/blgp: fp8 e4m3 A and B
                    0, 0x7f7f7f7f,           // opsel_a, scale_a = 1.0 (E8M0 127)
                    0, 0x7f7f7f7f);          // opsel_b, scale_b = 1.0
        }
        __syncthreads();   // protect LDS before next stage overwrites
    }

    // ---- epilogue: column partial sums ----
    // C/D layout shape-determined: col = c16, row = quad*4 + r  [m89/m127/m128]
    float sqi[4][4];
    #pragma unroll
    for (int tm = 0; tm < 4; ++tm)
        #pragma unroll
        for (int r = 0; r < 4; ++r)
            sqi[tm][r] = sq[i0 + wm * 64 + tm * 16 + quad * 4 + r];
    float sqj[4];
    #pragma unroll
    for (int tn = 0; tn < 4; ++tn)
        sqj[tn] = sq[j0 + wn * 64 + tn * 16 + c16];

    float cpa[4], cna[4], cpb[4], cnb[4], cpd[4], cnd[4];
    const bool diag = (bi == bj);   // same-class pairs only occur here (8 | 128)
    const float DS = -0.001953125f; // -2 * 2^-10: undo x32 input scaling

    #pragma unroll
    for (int tn = 0; tn < 4; ++tn) {
        float pa = 0.f, na = 0.f, pb = 0.f, nb = 0.f, pd = 0.f, nd = 0.f;
        if (!diag) {
            // pure negatives: branch-free
            #pragma unroll
            for (int tm = 0; tm < 4; ++tm)
                #pragma unroll
                for (int r = 0; r < 4; ++r) {
                    float dot = acc[tm][tn][r];
                    float dsq = fmaf(dot, DS, sqi[tm][r] + sqj[tn]);
                    float dist = sqrtf(fmaxf(dsq, 1e-12f));
                    float t = __expf(20.0f * (1.1f - dist));   // exp(BETA(1.1-d))
                    na = fmaf(t, t, na);                        // e^4 * exp(40(1-d))
                    nb += t;
                    nd += dist;
                }
        } else {
            const int gj = j0 + wn * 64 + tn * 16 + c16;
            const int gjc = gj >> 3;
            #pragma unroll
            for (int tm = 0; tm < 4; ++tm)
                #pragma unroll
                for (int r = 0; r < 4; ++r) {
                    const int gi = i0 + wm * 64 + tm * 16 + quad * 4 + r;
                    float dot = acc[tm][tn][r];
                    float dsq = fmaf(dot, DS, sqi[tm][r] + sqj[tn]);
                    float dist = sqrtf(fmaxf(dsq, 1e-12f));
                    float t = __expf(20.0f * (1.1f - dist));
                    bool same = (gi >> 3) == gjc;
                    if (same) {
                        if (gi != gj) {
                            pa = fmaf(t, t, pa);
                            pb += __expf(20.0f * (dist - 0.8f));
                            pd += dist;
                        }
                    } else {
                        na = fmaf(t, t, na);
                        nb += t;
                        nd += dist;
                    }
                }
        }
        cpa[tn] = pa; cna[tn] = na; cpb[tn] = pb;
        cnb[tn] = nb; cpd[tn] = pd; cnd[tn] = nd;
    }

    // reduce the 4 quads (each column's 64 rows): lanes ^16, ^32 only
    #pragma unroll
    for (int tn = 0; tn < 4; ++tn) {
        #pragma unroll
        for (int s = 16; s < 64; s <<= 1) {
            cna[tn] += __shfl_xor(cna[tn], s);
            cnb[tn] += __shfl_xor(cnb[tn], s);
            cnd[tn] += __shfl_xor(cnd[tn], s);
        }
        if (diag) {
            #pragma unroll
            for (int s = 16; s < 64; s <<= 1) {
                cpa[tn] += __shfl_xor(cpa[tn], s);
                cpb[tn] += __shfl_xor(cpb[tn], s);
                cpd[tn] += __shfl_xor(cpd[tn], s);
            }
        }
    }

    // combine the two wm halves via LDS (smem is free after last barrier)
    float* colBuf = (float*)smem;   // [2][128][6] floats = 6 KB
    #pragma unroll
    for (int tn = 0; tn < 4; ++tn) {
        // all 4 quads hold identical reduced values; same-addr same-value writes
        int cb = (wm * 128 + wn * 64 + tn * 16 + c16) * 6;
        colBuf[cb + 0] = cpa[tn]; colBuf[cb + 1] = cna[tn];
        colBuf[cb + 2] = cpb[tn]; colBuf[cb + 3] = cnb[tn];
        colBuf[cb + 4] = cpd[tn]; colBuf[cb + 5] = cnd[tn];
    }
    __syncthreads();

    // atomic-free partial store: contiguous 3 KB per block
    float* dst = colPart + (size_t)bi * N * 6 + (size_t)j0 * 6;
    #pragma unroll
    for (int it = 0; it < 3; ++it) {
        int idx = it * 256 + tid;               // 0..767
        dst[idx] = colBuf[idx] + colBuf[768 + idx];
    }
}

// ---------------------------------------------------------------------------
// Kernel 3: reduce the 32 per-block partial slots -> per-row loss pieces,
// then block-reduce and atomically accumulate the 3 global means into out.
// (out zero-initialized by prep_kernel; stream serialization guarantees order)
// ---------------------------------------------------------------------------
__global__ __launch_bounds__(256) void reduce_finalize(const float* __restrict__ colPart,
                                                       float* __restrict__ out) {
    int j = blockIdx.x * 256 + threadIdx.x;     // 4096 threads total
    float pa = 0.f, na = 0.f, pb = 0.f, nb = 0.f, pd = 0.f, nd = 0.f;
    for (int s = 0; s < NSLOT; ++s) {
        const float* p = colPart + (size_t)s * N * 6 + (size_t)j * 6;
        pa += p[0]; na += p[1]; pb += p[2];
        nb += p[3]; pd += p[4]; nd += p[5];
    }
    // pa/na both carry the same e^4 factor vs exp(40(1-d)) -> cancels in a_lr
    float a_lr = 1.0f - pa / (pa + na);
    float L = a_lr * (logf(pb) + logf(nb));

    #pragma unroll
    for (int s = 1; s < 64; s <<= 1) {
        L  += __shfl_xor(L, s);
        pd += __shfl_xor(pd, s);
        nd += __shfl_xor(nd, s);
    }
    __shared__ float r0[4], r1[4], r2[4];
    int lane = threadIdx.x & 63, w = threadIdx.x >> 6;
    if (lane == 0) { r0[w] = L; r1[w] = pd; r2[w] = nd; }
    __syncthreads();
    if (threadIdx.x == 0) {
        float Ls = r0[0] + r0[1] + r0[2] + r0[3];
        float Ps = r1[0] + r1[1] + r1[2] + r1[3];
        float Gs = r2[0] + r2[1] + r2[2] + r2[3];
        atomicAdd(out + 0, Ls / (float)N);
        atomicAdd(out + 2, Ps / ((float)N * 7.0f));              // 7 pos pairs/row
        atomicAdd(out + 3, Gs / ((float)N * (float)(N - 8)));    // 4088 neg/row
        // out[1] (accuracy) stays 0 from prep's init
    }
}

// ---------------------------------------------------------------------------
extern "C" void kernel_launch(void* const* d_in, const int* in_sizes, int n_in,
                              void* d_out, int out_size, void* d_ws, size_t ws_size,
                              hipStream_t stream) {
    const float* x = (const float*)d_in[0];
    float* out = (float*)d_out;
    char* ws = (char*)d_ws;

    unsigned char* xq = (unsigned char*)ws;                          // 4 MB fp8 matrix
    float* sq         = (float*)(ws + (size_t)N * D);                // 16 KB row norms
    float* colPart    = (float*)(ws + (size_t)N * D + N * 4);        // 3 MB partials

    prep_kernel<<<N / 4, 256, 0, stream>>>(x, xq, sq, out);

    dim3 grid(N / BN, N / BM);
    gemm_fused<<<grid, 256, 0, stream>>>(xq, sq, colPart);

    reduce_finalize<<<N / 256, 256, 0, stream>>>(colPart, out);
}